// Round 4
// baseline (11673.148 us; speedup 1.0000x reference)
//
#include <hip/hip_runtime.h>
#include <hip/hip_bf16.h>
#include <cstdint>
#include <cstddef>

// Model_69647189672235: GRU encoder-decoder w/ attention pooling.
// B=256 T=256 D=72 HID=512 H=1024, to_predict=10 (hardcoded; scalar input ignored).
// R4: R3 with the fence spelling fixed (__builtin_amdgcn_fence(..., "agent") —
// __hip_atomic_fence does not exist in this ROCm's headers).
// Persistent encoder: 512 step-launches -> 16 persistent launches (256 blocks x
// 64 thr, 1/CU) with custom device-scope grid barrier; per-step gh GEMM uses
// mfma_32x32x16 with frag-direct L2 loads from swizzled h/W layouts; gates fused
// in-epilogue via LDS relayout; fp32 h master in LDS.

using bf16 = __hip_bfloat16;
typedef __attribute__((ext_vector_type(8))) short short8;
typedef __attribute__((ext_vector_type(4))) float floatx4;
typedef __attribute__((ext_vector_type(16))) float floatx16;

#define B_    256
#define T_    256
#define D_    72
#define DP_   96      // D padded to mult of 32 for BK=32
#define HID_  512
#define H_    1024
#define H3_   3072
#define NPRED 10
#define CHUNK 16      // encoder timesteps per xp GEMM / persistent launch
#define RA    8192    // rows per slab in chunked full-size GEMMs
#define NBLK  256     // persistent encoder grid

__device__ __forceinline__ float b2f(bf16 v){ return __bfloat162float(v); }
__device__ __forceinline__ bf16  f2b(float v){ return __float2bfloat16(v); }
__device__ __forceinline__ float s2f(short s){
  union { unsigned u; float f; } v; v.u = ((unsigned)(unsigned short)s) << 16; return v.f;
}

__device__ __forceinline__ void async_ld16(const bf16* g, bf16* l) {
  __builtin_amdgcn_global_load_lds(
      (const __attribute__((address_space(1))) unsigned int*)g,
      (__attribute__((address_space(3))) unsigned int*)l,
      16, 0, 0);
}

enum { EPI_F32 = 0, EPI_BF16 = 1, EPI_BF16_RELU = 2, EPI_BF16_RELU_PERM = 3 };

// C = epi(A @ B^T + bias). A:[M,K] bf16 row-major, B:[N,K] bf16 row-major.
template<int BM, int BN, int WM, int WN, int EPI>
__global__ __launch_bounds__(256, 2) void gemm_bt(
    const bf16* __restrict__ A, const bf16* __restrict__ B,
    const float* __restrict__ bias, void* __restrict__ Cout,
    int M, int N, int K, int row_off)
{
  constexpr int BK = 32;
  constexpr int NWN = BN / WN;
  constexpr int MT = WM / 16, NT = WN / 16;
  constexpr int ASEG = BM * 4;
  constexpr int TSEG = (BM + BN) * 4;
  static_assert((BM/WM)*(BN/WN) == 4, "4 waves");
  static_assert(TSEG % 256 == 0, "uniform staging");

  __shared__ __align__(16) bf16 smem[(BM + BN) * BK];
  bf16* As = smem;
  bf16* Bs = smem + BM * BK;

  const int tid  = threadIdx.x;
  const int lane = tid & 63;
  const int wave = tid >> 6;
  const int wm = wave / NWN, wn = wave % NWN;
  const int m0 = blockIdx.y * BM, n0 = blockIdx.x * BN;

  floatx4 acc[MT][NT];
#pragma unroll
  for (int i = 0; i < MT; i++)
#pragma unroll
    for (int j = 0; j < NT; j++)
      acc[i][j] = floatx4{0.f, 0.f, 0.f, 0.f};

  const int krow = (lane >> 4) << 3;
  const int r16  = lane & 15;

  for (int k0 = 0; k0 < K; k0 += BK) {
    __syncthreads();
#pragma unroll
    for (int it = 0; it < TSEG / 256; it++) {
      int s = tid + it * 256;
      const bf16* g;
      if (s < ASEG) {
        int row = s >> 2, kseg = s & 3;
        g = A + (size_t)(m0 + row) * K + k0 + kseg * 8;
      } else {
        int s2 = s - ASEG;
        int row = s2 >> 2, kseg = s2 & 3;
        g = B + (size_t)(n0 + row) * K + k0 + kseg * 8;
      }
      async_ld16(g, smem + (size_t)s * 8);
    }
    __syncthreads();
    short8 af[MT], bfr[NT];
#pragma unroll
    for (int i = 0; i < MT; i++)
      af[i] = *(const short8*)(As + (wm * WM + i * 16 + r16) * BK + krow);
#pragma unroll
    for (int j = 0; j < NT; j++)
      bfr[j] = *(const short8*)(Bs + (wn * WN + j * 16 + r16) * BK + krow);
#pragma unroll
    for (int i = 0; i < MT; i++)
#pragma unroll
      for (int j = 0; j < NT; j++)
        acc[i][j] = __builtin_amdgcn_mfma_f32_16x16x32_bf16(af[i], bfr[j], acc[i][j], 0, 0, 0);
  }

#pragma unroll
  for (int i = 0; i < MT; i++) {
#pragma unroll
    for (int j = 0; j < NT; j++) {
      int gn = n0 + wn * WN + j * 16 + r16;
      float bv = bias ? bias[gn] : 0.f;
#pragma unroll
      for (int r = 0; r < 4; r++) {
        int gm = m0 + wm * WM + i * 16 + ((lane >> 4) << 2) + r;
        float v = acc[i][j][r] + bv;
        if (EPI == EPI_BF16_RELU || EPI == EPI_BF16_RELU_PERM) v = fmaxf(v, 0.f);
        size_t orow;
        if (EPI == EPI_BF16_RELU_PERM) {
          int g = row_off + gm;
          orow = (size_t)(g & 255) * 256 + (size_t)(g >> 8);
        } else {
          orow = (size_t)gm;
        }
        if (EPI == EPI_F32) ((float*)Cout)[orow * (size_t)N + gn] = v;
        else                ((bf16*) Cout)[orow * (size_t)N + gn] = f2b(v);
      }
    }
  }
}

__global__ void convert_pad(const float* __restrict__ in, bf16* __restrict__ out,
                            int rows, int kin, int kout)
{
  size_t idx = (size_t)blockIdx.x * blockDim.x + threadIdx.x;
  if (idx >= (size_t)rows * kout) return;
  int r = idx / kout, c = idx % kout;
  out[idx] = (c < kin) ? f2b(in[(size_t)r * kin + c]) : f2b(0.f);
}

__global__ void zero_u32(unsigned* __restrict__ p, int n)
{
  int idx = blockIdx.x * blockDim.x + threadIdx.x;
  if (idx < n) p[idx] = 0u;
}

// enc_whh [3072][1024] fp32 -> B-frag-contiguous swizzle:
// wsw[plane = (k>>4)*2 + ((k>>3)&1)][n][k&7], 8 bf16 (16B) per (plane,n)
__global__ void wsw_k(const float* __restrict__ w, bf16* __restrict__ wsw)
{
  int idx = blockIdx.x * blockDim.x + threadIdx.x;  // over H3_*H_
  int n = idx >> 10, k = idx & (H_ - 1);
  int plane = (k >> 4) * 2 + ((k >> 3) & 1);
  wsw[((size_t)plane * H3_ + n) * 8 + (k & 7)] = f2b(w[idx]);
}

__device__ __forceinline__ float sigm(float v){ return 1.f / (1.f + __expf(-v)); }

// Persistent encoder chunk: 16 GRU steps, 256 blocks x 64 threads (1 wave).
// Block (mi,jt): m rows [mi*32,+32), j cols [jt*32,+32), all 3 gates.
// blockIdx = mi*32+jt -> XCD = blockIdx%8 = jt%8: same-jt blocks share an XCD,
// keeping that jt's 96 W-rows (192KB) L2-resident across all steps.
// h swizzled double-buffer: hsw[plane=(j>>4)*2+((j>>3)&1)][m][j&7].
__global__ __launch_bounds__(64, 1) void enc_chunk(
    const bf16* __restrict__ xpc,   // [CHUNK*256, 3072] gi (bias included)
    const bf16* __restrict__ Wsw,   // [128][3072][8]
    bf16* hswA, bf16* hswB,         // swizzled h, double buffer
    float* __restrict__ h32save,    // [256][1024] fp32 master (chunk boundary)
    bf16* __restrict__ enc_out,     // t-major [t*256+b][1024]
    const float* __restrict__ bhh,  // [3072]
    unsigned* bar, int tc)
{
  const int lane = threadIdx.x;
  const int mi = blockIdx.x >> 5, jt = blockIdx.x & 31;
  const int m0 = mi * 32, j0 = jt * 32;
  const int col = lane & 31, half = lane >> 5;
  const int row = lane >> 1, ch = lane & 1, coff = ch * 16;

  __shared__ float ghs[3][32][33];   // gh relayout, +1 pad (2-way max)
  __shared__ float h32m[32][33];     // fp32 h master tile

  {
    const float* src = h32save + (size_t)(m0 + row) * H_ + j0 + coff;
#pragma unroll
    for (int e = 0; e < 16; e++) h32m[row][coff + e] = src[e];
  }
  __syncthreads();

  const float b_r = bhh[j0 + col];
  const float b_z = bhh[H_ + j0 + col];
  const float b_n = bhh[2 * H_ + j0 + col];

  // frag-load bases (element units; every address 16B-aligned)
  const size_t a_base = ((size_t)half * 256 + (m0 + col)) * 8;
  const size_t w_base = ((size_t)half * H3_ + (j0 + col)) * 8;

  for (int tt = 0; tt < CHUNK; tt++) {
    const bf16* hr = (tt & 1) ? hswB : hswA;
    bf16*       hw = (tt & 1) ? hswA : hswB;

    floatx16 ar, az, an;
#pragma unroll
    for (int r = 0; r < 16; r++) { ar[r] = b_r; az[r] = b_z; an[r] = b_n; }

    // gh = h @ Whh^T : K=1024 = 64 k-steps of 16, frags straight from L2
#pragma unroll 4
    for (int ks = 0; ks < 64; ks++) {
      short8 a  = *(const short8*)(hr  + a_base + (size_t)ks * 2 * 256 * 8);
      const bf16* wp = Wsw + w_base + (size_t)ks * 2 * H3_ * 8;
      short8 wr = *(const short8*)(wp);
      short8 wz = *(const short8*)(wp + (size_t)H_ * 8);
      short8 wn = *(const short8*)(wp + (size_t)2 * H_ * 8);
      ar = __builtin_amdgcn_mfma_f32_32x32x16_bf16(a, wr, ar, 0, 0, 0);
      az = __builtin_amdgcn_mfma_f32_32x32x16_bf16(a, wz, az, 0, 0, 0);
      an = __builtin_amdgcn_mfma_f32_32x32x16_bf16(a, wn, an, 0, 0, 0);
    }

    // acc (col=lane&31, row=(r&3)+8*(r>>2)+4*half [m74/m101]) -> LDS row layout
#pragma unroll
    for (int r = 0; r < 16; r++) {
      int rr = (r & 3) + 8 * (r >> 2) + 4 * half;
      ghs[0][rr][col] = ar[r];
      ghs[1][rr][col] = az[r];
      ghs[2][rr][col] = an[r];
    }
    __syncthreads();

    // gates: thread = (row, 16-col half), fp32 master in LDS
    const bf16* gp = xpc + ((size_t)(tt * 256 + m0 + row) * H3_ + j0 + coff);
    short gtmp[3][16];
#pragma unroll
    for (int g = 0; g < 3; g++) {
      *(short8*)&gtmp[g][0] = *(const short8*)(gp + (size_t)g * H_);
      *(short8*)&gtmp[g][8] = *(const short8*)(gp + (size_t)g * H_ + 8);
    }
    short hb[16];
#pragma unroll
    for (int e = 0; e < 16; e++) {
      float rr = sigm(s2f(gtmp[0][e]) + ghs[0][row][coff + e]);
      float zz = sigm(s2f(gtmp[1][e]) + ghs[1][row][coff + e]);
      float nn = tanhf(s2f(gtmp[2][e]) + rr * ghs[2][row][coff + e]);
      float hnew = (1.f - zz) * nn + zz * h32m[row][coff + e];
      h32m[row][coff + e] = hnew;
      bf16 hv = f2b(hnew);
      hb[e] = *(short*)&hv;
    }
    {
      bf16* op = enc_out + ((size_t)(tc * CHUNK + tt) * 256 + m0 + row) * H_ + j0 + coff;
      *(short8*)op       = *(short8*)&hb[0];
      *(short8*)(op + 8) = *(short8*)&hb[8];
    }
    {
      int plane = (jt * 2 + ch) * 2;   // j = j0+coff+e: (j>>4)=jt*2+ch, (j>>3)&1 = e>=8
      *(short8*)(hw + ((size_t)plane       * 256 + m0 + row) * 8) = *(short8*)&hb[0];
      *(short8*)(hw + ((size_t)(plane + 1) * 256 + m0 + row) * 8) = *(short8*)&hb[8];
    }

    if (tt < CHUNK - 1) {
      // device-scope grid barrier (co-residency: 256 tiny blocks on 256 CUs)
      __builtin_amdgcn_fence(__ATOMIC_RELEASE, "agent");
      if (lane == 0) {
        __hip_atomic_fetch_add(bar + tc, 1u, __ATOMIC_RELAXED, __HIP_MEMORY_SCOPE_AGENT);
        unsigned tgt = (unsigned)(tt + 1) * NBLK;
        long sp = 0;
        while (__hip_atomic_load(bar + tc, __ATOMIC_RELAXED, __HIP_MEMORY_SCOPE_AGENT) < tgt
               && sp < (1L << 28)) { sp++; __builtin_amdgcn_s_sleep(2); }
      }
      __builtin_amdgcn_fence(__ATOMIC_ACQUIRE, "agent");
      __syncthreads();
    } else {
      __syncthreads();
      float* dst = h32save + (size_t)(m0 + row) * H_ + j0 + coff;
#pragma unroll
      for (int e = 0; e < 16; e++) dst[e] = h32m[row][coff + e];
    }
  }
}

__global__ void ppad_init(const float* __restrict__ x, bf16* __restrict__ ppad)
{
  int idx = blockIdx.x * blockDim.x + threadIdx.x;  // over B_*DP_
  int b = idx / DP_, c = idx % DP_;
  float v = (c < D_) ? x[((size_t)b * T_ + (T_ - 1)) * D_ + c] : 0.f;
  ppad[idx] = f2b(v);
}

__global__ void dec_gates(const float* __restrict__ gi, const float* __restrict__ gh,
                          float* __restrict__ hs32, bf16* __restrict__ hs16)
{
  int idx = blockIdx.x * blockDim.x + threadIdx.x;
  int b = idx >> 10, j = idx & (H_ - 1);
  const float* gir = gi + (size_t)b * H3_;
  const float* ghr = gh + (size_t)b * H3_;
  float r = sigm(gir[j] + ghr[j]);
  float z = sigm(gir[j + H_] + ghr[j + H_]);
  float n = tanhf(gir[j + 2 * H_] + r * ghr[j + 2 * H_]);
  float hnew = (1.f - z) * n + z * hs32[idx];
  hs32[idx] = hnew;
  hs16[idx] = f2b(hnew);
}

__global__ void logits_mv(const bf16* __restrict__ ls1, const float* __restrict__ w2,
                          const float* __restrict__ b2, float* __restrict__ logits)
{
  int gw   = (blockIdx.x * blockDim.x + threadIdx.x) >> 6;
  int lane = threadIdx.x & 63;
  const bf16* row = ls1 + (size_t)gw * HID_;
  float s = 0.f;
#pragma unroll
  for (int k = lane; k < HID_; k += 64) s += b2f(row[k]) * w2[k];
#pragma unroll
  for (int off = 32; off > 0; off >>= 1) s += __shfl_down(s, off, 64);
  if (lane == 0) logits[gw] = s + b2[0];
}

__global__ void attention(const float* __restrict__ logits, const bf16* __restrict__ enc_out,
                          float* __restrict__ rep, float* __restrict__ hs32,
                          bf16* __restrict__ hs16)
{
  int b = blockIdx.x, t = threadIdx.x;
  __shared__ float w[T_];
  __shared__ float red[T_];
  float lg = logits[(size_t)t * B_ + b];
  red[t] = lg; __syncthreads();
  for (int s = 128; s > 0; s >>= 1) { if (t < s) red[t] = fmaxf(red[t], red[t + s]); __syncthreads(); }
  float mx = red[0]; __syncthreads();
  float e = __expf(lg - mx);
  w[t] = e; red[t] = e; __syncthreads();
  for (int s = 128; s > 0; s >>= 1) { if (t < s) red[t] += red[t + s]; __syncthreads(); }
  float inv = 1.f / red[0];
  float acc[4] = {0.f, 0.f, 0.f, 0.f};
  for (int tt = 0; tt < T_; tt++) {
    float wt = w[tt] * inv;
    const bf16* row = enc_out + ((size_t)tt * B_ + b) * H_;
#pragma unroll
    for (int i = 0; i < 4; i++) acc[i] += wt * b2f(row[t + i * 256]);
  }
#pragma unroll
  for (int i = 0; i < 4; i++) {
    int j = t + i * 256;
    rep [(size_t)b * H_ + j] = acc[i];
    hs32[(size_t)b * H_ + j] = acc[i];
    hs16[(size_t)b * H_ + j] = f2b(acc[i]);
  }
}

__global__ void pred_k(const bf16* __restrict__ e1, const float* __restrict__ w2,
                       const float* __restrict__ b2, float* __restrict__ out,
                       bf16* __restrict__ ppad, int s)
{
  int b = blockIdx.x, t = threadIdx.x;
  __shared__ float ev[HID_];
  for (int k = t; k < HID_; k += 256) ev[k] = b2f(e1[(size_t)b * HID_ + k]);
  __syncthreads();
  if (t < D_) {
    float acc = b2[t];
    const float* wr = w2 + (size_t)t * HID_;
    for (int k = 0; k < HID_; k++) acc += ev[k] * wr[k];
    out[(size_t)b * (NPRED * D_) + s * D_ + t] = acc;
    ppad[b * DP_ + t] = f2b(acc);
  }
}

extern "C" void kernel_launch(void* const* d_in, const int* in_sizes, int n_in,
                              void* d_out, int out_size, void* d_ws, size_t ws_size,
                              hipStream_t stream)
{
  const float* x       = (const float*)d_in[0];
  const float* p2l_w1  = (const float*)d_in[2];
  const float* p2l_b1  = (const float*)d_in[3];
  const float* p2l_w2  = (const float*)d_in[4];
  const float* p2l_b2  = (const float*)d_in[5];
  const float* enc_wih = (const float*)d_in[6];
  const float* enc_whh = (const float*)d_in[7];
  const float* enc_bih = (const float*)d_in[8];
  const float* enc_bhh = (const float*)d_in[9];
  const float* dec_wih = (const float*)d_in[10];
  const float* dec_whh = (const float*)d_in[11];
  const float* dec_bih = (const float*)d_in[12];
  const float* dec_bhh = (const float*)d_in[13];
  const float* l2p_w1  = (const float*)d_in[14];
  const float* l2p_b1  = (const float*)d_in[15];
  const float* l2p_w2  = (const float*)d_in[16];
  const float* l2p_b2  = (const float*)d_in[17];
  const float* l2s_w1  = (const float*)d_in[18];
  const float* l2s_b1  = (const float*)d_in[19];
  const float* l2s_w2  = (const float*)d_in[20];
  const float* l2s_b2  = (const float*)d_in[21];

  float* out_preds = (float*)d_out;
  float* out_rep   = (float*)d_out + (size_t)B_ * NPRED * D_;

  char* p = (char*)d_ws;
  auto alloc = [&](size_t bytes) -> char* {
    char* r = p; p += (bytes + 255) & ~(size_t)255; return r;
  };
  bf16* w_p2l1 = (bf16*)alloc((size_t)HID_ * DP_ * 2);
  bf16* w_p2l2 = (bf16*)alloc((size_t)H_ * HID_ * 2);
  bf16* w_ewih = (bf16*)alloc((size_t)H3_ * H_ * 2);
  bf16* Wsw    = (bf16*)alloc((size_t)H3_ * H_ * 2);   // swizzled enc_whh
  bf16* w_dwih = (bf16*)alloc((size_t)H3_ * H_ * 2);
  bf16* w_dwhh = (bf16*)alloc((size_t)H3_ * H_ * 2);
  bf16* w_l2p1 = (bf16*)alloc((size_t)HID_ * H_ * 2);
  bf16* w_l2s1 = (bf16*)alloc((size_t)HID_ * H_ * 2);
  bf16* latent = (bf16*)alloc((size_t)B_ * T_ * H_ * 2);   // t-major; aliased enc_out
  char* scratch = alloc((size_t)CHUNK * B_ * H3_ * 2);     // 25.2MB union
  bf16* xb   = (bf16*)scratch;                               // [TB, DP]
  bf16* tmpc = (bf16*)(scratch + (size_t)B_ * T_ * DP_ * 2); // [RA, HID]
  bf16* xpc  = (bf16*)scratch;                               // [CHUNK*B, H3]
  bf16* lsc  = (bf16*)scratch;                               // [RA, HID]
  bf16* hsw0  = (bf16*)alloc((size_t)B_ * H_ * 2);
  bf16* hsw1  = (bf16*)alloc((size_t)B_ * H_ * 2);
  float* h32s = (float*)alloc((size_t)B_ * H_ * 4);
  float* ghb  = (float*)alloc((size_t)B_ * H3_ * 4);
  float* gib  = (float*)alloc((size_t)B_ * H3_ * 4);
  float* hs32 = (float*)alloc((size_t)B_ * H_ * 4);
  bf16*  hs16 = (bf16*) alloc((size_t)B_ * H_ * 2);
  float* logit= (float*)alloc((size_t)B_ * T_ * 4);
  bf16*  d1   = (bf16*) alloc((size_t)B_ * HID_ * 2);
  bf16*  inp  = (bf16*) alloc((size_t)B_ * H_ * 2);
  bf16*  e1   = (bf16*) alloc((size_t)B_ * HID_ * 2);
  bf16*  ppad = (bf16*) alloc((size_t)B_ * DP_ * 2);
  unsigned* bar = (unsigned*)alloc(64 * 4);
  bf16*  enc_out = latent;

  if ((size_t)(p - (char*)d_ws) > ws_size) return;  // ~193 MB needed

  const int TB = B_ * T_;

  auto cgrid = [](size_t n) { return dim3((unsigned)((n + 255) / 256)); };
  // zero: barrier slots, h32 master, initial swizzled h
  zero_u32<<<1, 64, 0, stream>>>(bar, 64);
  zero_u32<<<cgrid((size_t)B_ * H_), 256, 0, stream>>>((unsigned*)h32s, B_ * H_);
  zero_u32<<<cgrid((size_t)B_ * H_ / 2), 256, 0, stream>>>((unsigned*)hsw0, B_ * H_ / 2);

  convert_pad<<<cgrid((size_t)TB * DP_),   256, 0, stream>>>(x,       xb,     TB,   D_,   DP_);
  convert_pad<<<cgrid((size_t)HID_ * DP_), 256, 0, stream>>>(p2l_w1,  w_p2l1, HID_, D_,   DP_);
  convert_pad<<<cgrid((size_t)H_ * HID_),  256, 0, stream>>>(p2l_w2,  w_p2l2, H_,   HID_, HID_);
  convert_pad<<<cgrid((size_t)H3_ * H_),   256, 0, stream>>>(enc_wih, w_ewih, H3_,  H_,   H_);
  wsw_k     <<<cgrid((size_t)H3_ * H_),    256, 0, stream>>>(enc_whh, Wsw);
  convert_pad<<<cgrid((size_t)H3_ * H_),   256, 0, stream>>>(dec_wih, w_dwih, H3_,  H_,   H_);
  convert_pad<<<cgrid((size_t)H3_ * H_),   256, 0, stream>>>(dec_whh, w_dwhh, H3_,  H_,   H_);
  convert_pad<<<cgrid((size_t)HID_ * H_),  256, 0, stream>>>(l2p_w1,  w_l2p1, HID_, H_,   H_);
  convert_pad<<<cgrid((size_t)HID_ * H_),  256, 0, stream>>>(l2s_w1,  w_l2s1, HID_, H_,   H_);

  // par2lat(x) in slabs -> latent (t-major)
  for (int rc = 0; rc < TB / RA; rc++) {
    { dim3 g(HID_ / 128, RA / 128);
      gemm_bt<128,128,64,64,EPI_BF16_RELU><<<g, 256, 0, stream>>>(
          xb + (size_t)rc * RA * DP_, w_p2l1, p2l_b1, tmpc, RA, HID_, DP_, 0); }
    { dim3 g(H_ / 128, RA / 128);
      gemm_bt<128,128,64,64,EPI_BF16_RELU_PERM><<<g, 256, 0, stream>>>(
          tmpc, w_p2l2, p2l_b2, latent, RA, H_, HID_, rc * RA); }
  }

  // encoder: per chunk, xp GEMM then persistent 16-step kernel
  for (int tc = 0; tc < T_ / CHUNK; tc++) {
    dim3 g(H3_ / 128, (CHUNK * B_) / 128);
    gemm_bt<128,128,64,64,EPI_BF16><<<g, 256, 0, stream>>>(
        latent + (size_t)tc * CHUNK * B_ * H_, w_ewih, enc_bih, xpc,
        CHUNK * B_, H3_, H_, 0);
    enc_chunk<<<NBLK, 64, 0, stream>>>(
        xpc, Wsw, hsw0, hsw1, h32s, enc_out, enc_bhh, bar, tc);
  }

  // attention pooling (chunked score path) -> Rep + hs
  for (int rc = 0; rc < TB / RA; rc++) {
    dim3 g(HID_ / 128, RA / 128);
    gemm_bt<128,128,64,64,EPI_BF16_RELU><<<g, 256, 0, stream>>>(
        enc_out + (size_t)rc * RA * H_, w_l2s1, l2s_b1, lsc, RA, HID_, H_, 0);
    logits_mv<<<RA / 4, 256, 0, stream>>>(lsc, l2s_w2, l2s_b2, logit + (size_t)rc * RA);
  }
  attention<<<B_, 256, 0, stream>>>(logit, enc_out, out_rep, hs32, hs16);

  // autoregressive decoder
  ppad_init<<<(B_ * DP_) / 256, 256, 0, stream>>>(x, ppad);
  for (int s = 0; s < NPRED; s++) {
    { dim3 g(HID_ / 128, B_ / 64);
      gemm_bt<64,128,32,64,EPI_BF16_RELU><<<g, 256, 0, stream>>>(ppad, w_p2l1, p2l_b1, d1, B_, HID_, DP_, 0); }
    { dim3 g(H_ / 128, B_ / 64);
      gemm_bt<64,128,32,64,EPI_BF16_RELU><<<g, 256, 0, stream>>>(d1, w_p2l2, p2l_b2, inp, B_, H_, HID_, 0); }
    { dim3 g(H3_ / 128, B_ / 64);
      gemm_bt<64,128,32,64,EPI_F32><<<g, 256, 0, stream>>>(inp, w_dwih, dec_bih, gib, B_, H3_, H_, 0); }
    { dim3 g(H3_ / 128, B_ / 64);
      gemm_bt<64,128,32,64,EPI_F32><<<g, 256, 0, stream>>>(hs16, w_dwhh, dec_bhh, ghb, B_, H3_, H_, 0); }
    dec_gates<<<(B_ * H_) / 256, 256, 0, stream>>>(gib, ghb, hs32, hs16);
    { dim3 g(HID_ / 128, B_ / 64);
      gemm_bt<64,128,32,64,EPI_BF16_RELU><<<g, 256, 0, stream>>>(hs16, w_l2p1, l2p_b1, e1, B_, HID_, H_, 0); }
    pred_k<<<B_, 256, 0, stream>>>(e1, l2p_w2, l2p_b2, out_preds, ppad, s);
  }
}